// Round 4
// baseline (258.379 us; speedup 1.0000x reference)
//
#include <hip/hip_runtime.h>

typedef _Float16 h8_t __attribute__((ext_vector_type(8)));
typedef _Float16 h4_t __attribute__((ext_vector_type(4)));
typedef float f32x4 __attribute__((ext_vector_type(4)));

#define NB 64
#define NH 8
#define NL 2048
#define ND 512
// flat K matrix rows: NB*NL = 131072

// swizzled half-index into a [rows][32]-fp16 tile: XOR 16B-chunk with row bits
__device__ __forceinline__ int swz_idx(int row, int chunk) {
    return row * 32 + ((chunk ^ ((row >> 1) & 3)) << 3);
}

// ---------------- Kernel 1: Wq = Q @ Ww.T + Wb  (f32, tiny) ----------------
__global__ __launch_bounds__(256) void wq_kernel(const float* __restrict__ Q,
                                                 const float* __restrict__ Ww,
                                                 const float* __restrict__ Wb,
                                                 float* __restrict__ Wq) {
    __shared__ float q[ND];
    const int b = blockIdx.x;
    const int t = threadIdx.x;
    for (int i = t; i < ND; i += 256) q[i] = Q[b * ND + i];
    __syncthreads();
    for (int j = t; j < ND; j += 256) {
        const float* wr = Ww + (size_t)j * ND;
        float acc = 0.f;
        for (int k = 0; k < ND; k += 4) {
            float4 w = *(const float4*)(wr + k);
            acc += q[k] * w.x + q[k + 1] * w.y + q[k + 2] * w.z + q[k + 3] * w.w;
        }
        Wq[b * ND + j] = acc + Wb[j];
    }
}

// ---------------- Kernel 2: convert Uw (f32) -> fp16 (RNE) ----------------
__global__ __launch_bounds__(256) void cvt_uw_kernel(const float* __restrict__ Uw,
                                                     _Float16* __restrict__ UwH) {
    const size_t i = ((size_t)blockIdx.x * 256 + threadIdx.x) * 4;
    float4 v = *(const float4*)(Uw + i);
    h4_t h = {(_Float16)v.x, (_Float16)v.y, (_Float16)v.z, (_Float16)v.w};
    *(h4_t*)(UwH + i) = h;
}

// ---------------- Kernel 3: Uk GEMM (fp16 MFMA) + tanh-reduce -> scores ----------------
// BM=64, BN=256, BK=32. 4 waves (1m x 4n), wave tile 64x64. Grid 4096.
// A (f32, HBM): reg-staged 2 steps ahead -> cvt fp16 -> swizzled LDS (double buf).
// B (fp16, L2): per-wave register fragments, double-buffered 1 step ahead. NO LDS.
// Raw s_barrier + lgkmcnt(0) only -- no vmcnt(0) drain, loads stay in flight.
__global__ __launch_bounds__(256) void uk_score_kernel(
    const float* __restrict__ Km,       // [131072][512] f32
    const _Float16* __restrict__ UwH,   // [512][512] fp16
    const float* __restrict__ Ub,       // [512]
    const float* __restrict__ Wq,       // [64][512]
    const float* __restrict__ Vw,       // [64]
    const float* __restrict__ Vb,       // [1]
    float* __restrict__ scores)         // [512][2048]
{
    __shared__ __align__(16) _Float16 Al[2][64 * 32];   // 2 x 4 KB

    const int t = threadIdx.x;
    const int lane = t & 63;
    const int wn = t >> 6;            // 0..3 (n-split; all waves share the A rows)

    // XCD swizzle: each XCD gets a contiguous tm slab; tn-pairs adjacent in time
    const int bid = blockIdx.x;                      // 4096 blocks
    const int swz = (bid & 7) * 512 + (bid >> 3);    // bijective
    const int tn = swz & 1;
    const int tm = swz >> 1;                         // 0..2047
    const size_t row0 = (size_t)tm * 64;
    const int n0 = tn * 256;

    f32x4 acc[4][4];
#pragma unroll
    for (int i = 0; i < 4; ++i)
#pragma unroll
        for (int j = 0; j < 4; ++j) acc[i][j] = (f32x4){0.f, 0.f, 0.f, 0.f};

    // A staging: thread t covers row (t>>2), 8-half chunk (t&3)
    const int arow = t >> 2;          // 0..63
    const int achunk = t & 3;
    const float* gA = Km + (row0 + arow) * (size_t)ND + achunk * 8;
    const int a_dst = swz_idx(arow, achunk);

    const int col16 = lane & 15;
    const int kg = lane >> 4;         // 0..3 = k-chunk

    // B fragment base pointers (per-lane, k-contiguous rows of UwH)
    const _Float16* gB[4];
#pragma unroll
    for (int j = 0; j < 4; ++j)
        gB[j] = UwH + (size_t)(n0 + wn * 64 + j * 16 + col16) * ND + kg * 8;

    h8_t bf[2][4];
    float4 rA[2][2];

    // ---- prologue: A(0) immediate, A(1) -> rA[1], bf(0) -> bf[0] ----
    {
        float4 p0 = *(const float4*)(gA);
        float4 p1 = *(const float4*)(gA + 4);
        rA[1][0] = *(const float4*)(gA + 32);
        rA[1][1] = *(const float4*)(gA + 36);
#pragma unroll
        for (int j = 0; j < 4; ++j) bf[0][j] = *(const h8_t*)(gB[j]);
        h8_t ah = {(_Float16)p0.x, (_Float16)p0.y, (_Float16)p0.z, (_Float16)p0.w,
                   (_Float16)p1.x, (_Float16)p1.y, (_Float16)p1.z, (_Float16)p1.w};
        *(h8_t*)&Al[0][a_dst] = ah;
    }
    asm volatile("s_waitcnt lgkmcnt(0)" ::: "memory");
    __builtin_amdgcn_s_barrier();
    __builtin_amdgcn_sched_barrier(0);

#pragma unroll
    for (int s = 0; s < 16; ++s) {
        const int b = s & 1;
        // issue A(s+2) -> rA[b] (free slot: A(s) was consumed at step s-1)
        if (s <= 13) {
            rA[b][0] = *(const float4*)(gA + (s + 2) * 32);
            rA[b][1] = *(const float4*)(gA + (s + 2) * 32 + 4);
        }
        // issue B(s+1) -> bf[1-b]
        if (s <= 14) {
#pragma unroll
            for (int j = 0; j < 4; ++j)
                bf[1 - b][j] = *(const h8_t*)(gB[j] + (s + 1) * 32);
        }
        // A fragments from LDS (current buffer)
        h8_t af[4];
#pragma unroll
        for (int i = 0; i < 4; ++i)
            af[i] = *(const h8_t*)&Al[b][swz_idx(i * 16 + col16, kg)];
        asm volatile("s_waitcnt lgkmcnt(0)" ::: "memory");
        __builtin_amdgcn_sched_barrier(0);
#pragma unroll
        for (int i = 0; i < 4; ++i)
#pragma unroll
            for (int j = 0; j < 4; ++j)
                acc[i][j] = __builtin_amdgcn_mfma_f32_16x16x32_f16(af[i], bf[b][j], acc[i][j], 0, 0, 0);
        // write-late: cvt A(s+1) (loaded at s-1, ~1.5 steps in flight) into next buffer
        if (s <= 14) {
            const float4 q0 = rA[1 - b][0];
            const float4 q1 = rA[1 - b][1];
            h8_t ah = {(_Float16)q0.x, (_Float16)q0.y, (_Float16)q0.z, (_Float16)q0.w,
                       (_Float16)q1.x, (_Float16)q1.y, (_Float16)q1.z, (_Float16)q1.w};
            *(h8_t*)&Al[1 - b][a_dst] = ah;
            asm volatile("s_waitcnt lgkmcnt(0)" ::: "memory");
            __builtin_amdgcn_s_barrier();
            __builtin_amdgcn_sched_barrier(0);
        }
    }

    // epilogue: score(row, jb) = sum_dh tanh(Uk + Wq + Ub) * Vw  (+Vb)
    const int b = (int)(row0 >> 11);
    const int h = ((int)row0 >> 8) & 7;
    const int i256b = (int)row0 & 255;

    float vw[4], wqv[4], ubv[4];
#pragma unroll
    for (int j = 0; j < 4; ++j) {
        const int jglob = n0 + wn * 64 + j * 16 + col16;  // 0..511
        const int dh = jglob & 63;
        vw[j] = Vw[dh];
        wqv[j] = Wq[b * ND + h * 64 + dh];
        ubv[j] = Ub[jglob];
    }
    const float vb0 = Vb[0];
    const int jb = tn * 4 + wn;       // 0..7
    const int bh = b * 8 + h;

#pragma unroll
    for (int i = 0; i < 4; ++i) {
#pragma unroll
        for (int r = 0; r < 4; ++r) {
            float s = 0.f;
#pragma unroll
            for (int j = 0; j < 4; ++j) {
                float x = acc[i][j][r] + wqv[j] + ubv[j];
                x = fminf(fmaxf(x, -15.f), 15.f);
                float e = __expf(2.f * x);
                s += ((e - 1.f) / (e + 1.f)) * vw[j];
            }
#pragma unroll
            for (int o = 8; o >= 1; o >>= 1) s += __shfl_xor(s, o);
            if (col16 == 0) {
                const int rloc = i * 16 + (lane >> 4) * 4 + r;
                const int m = (i256b + rloc) * 8 + jb;
                scores[(size_t)bh * NL + m] = s + vb0;
            }
        }
    }
}

// ---------------- Kernel 4: softmax -> dist (out) + attn = dist @ Kh ----------------
__global__ __launch_bounds__(256) void softmax_attn_kernel(
    const float* __restrict__ Km,
    const float* __restrict__ scores,
    float* __restrict__ out)  // [0,32768) attn, [32768,...) dist
{
    __shared__ float sd[NL];
    __shared__ float red[256];
    __shared__ float att[16][64];

    const int bh = blockIdx.x;
    const int b = bh >> 3, h = bh & 7;
    const int t = threadIdx.x;

    float loc[8];
    float mx = -1e30f;
#pragma unroll
    for (int j = 0; j < 8; ++j) {
        loc[j] = scores[(size_t)bh * NL + j * 256 + t];
        mx = fmaxf(mx, loc[j]);
    }
    red[t] = mx;
    __syncthreads();
    for (int s2 = 128; s2 > 0; s2 >>= 1) {
        if (t < s2) red[t] = fmaxf(red[t], red[t + s2]);
        __syncthreads();
    }
    mx = red[0];
    __syncthreads();
    float sum = 0.f;
#pragma unroll
    for (int j = 0; j < 8; ++j) {
        loc[j] = __expf(loc[j] - mx);
        sum += loc[j];
    }
    red[t] = sum;
    __syncthreads();
    for (int s2 = 128; s2 > 0; s2 >>= 1) {
        if (t < s2) red[t] += red[t + s2];
        __syncthreads();
    }
    const float inv = 1.f / red[0];
    __syncthreads();

    float* dist_out = out + 32768 + (size_t)bh * NL;
#pragma unroll
    for (int j = 0; j < 8; ++j) {
        float d = loc[j] * inv;
        sd[j * 256 + t] = d;
        dist_out[j * 256 + t] = d;
    }
    __syncthreads();

    const int wave = t >> 6, lane = t & 63;
    const int g = lane >> 4;
    const int c4 = (lane & 15) * 4;
    f32x4 acc = (f32x4){0.f, 0.f, 0.f, 0.f};
    const float* kb = Km + ((size_t)b * NL + h * 256) * ND;
    for (int rr = 0; rr < 16; ++rr) {
        const int row = wave * 64 + rr * 4 + g;
        const float* kr = kb + (size_t)row * ND;
#pragma unroll
        for (int jb2 = 0; jb2 < 8; ++jb2) {
            const float w = sd[row * 8 + jb2];
            float4 v = *(const float4*)(kr + jb2 * 64 + c4);
            acc[0] += w * v.x;
            acc[1] += w * v.y;
            acc[2] += w * v.z;
            acc[3] += w * v.w;
        }
    }
    *(f32x4*)&att[wave * 4 + g][c4] = acc;
    __syncthreads();
    if (t < 64) {
        float a = 0.f;
#pragma unroll
        for (int i = 0; i < 16; ++i) a += att[i][t];
        out[(size_t)b * ND + h * 64 + t] = a;
    }
}

extern "C" void kernel_launch(void* const* d_in, const int* in_sizes, int n_in,
                              void* d_out, int out_size, void* d_ws, size_t ws_size,
                              hipStream_t stream) {
    const float* Q  = (const float*)d_in[0];
    const float* Km = (const float*)d_in[1];
    const float* Ww = (const float*)d_in[2];
    const float* Wb = (const float*)d_in[3];
    const float* Uw = (const float*)d_in[4];
    const float* Ub = (const float*)d_in[5];
    const float* Vw = (const float*)d_in[6];
    const float* Vb = (const float*)d_in[7];
    float* out = (float*)d_out;

    char* ws = (char*)d_ws;
    float* scores = (float*)ws;                              // 4 MB
    float* Wq = (float*)(ws + 4194304);                      // 128 KB
    _Float16* UwH = (_Float16*)(ws + 4194304 + 131072);      // 512 KB

    wq_kernel<<<dim3(64), dim3(256), 0, stream>>>(Q, Ww, Wb, Wq);
    cvt_uw_kernel<<<dim3(256), dim3(256), 0, stream>>>(Uw, UwH);
    uk_score_kernel<<<dim3(4096), dim3(256), 0, stream>>>(Km, UwH, Ub, Wq, Vw, Vb, scores);
    softmax_attn_kernel<<<dim3(512), dim3(256), 0, stream>>>(Km, scores, out);
}

// Round 5
// 247.390 us; speedup vs baseline: 1.0444x; 1.0444x over previous
//
#include <hip/hip_runtime.h>

typedef _Float16 h8_t __attribute__((ext_vector_type(8)));
typedef _Float16 h4_t __attribute__((ext_vector_type(4)));
typedef float f32x4 __attribute__((ext_vector_type(4)));

#define NB 64
#define NH 8
#define NL 2048
#define ND 512
// flat K matrix rows: NB*NL = 131072

// ---------------- Kernel 1: Wq = Q @ Ww.T + Wb  (f32, tiny) ----------------
__global__ __launch_bounds__(256) void wq_kernel(const float* __restrict__ Q,
                                                 const float* __restrict__ Ww,
                                                 const float* __restrict__ Wb,
                                                 float* __restrict__ Wq) {
    __shared__ float q[ND];
    const int b = blockIdx.x;
    const int t = threadIdx.x;
    for (int i = t; i < ND; i += 256) q[i] = Q[b * ND + i];
    __syncthreads();
    for (int j = t; j < ND; j += 256) {
        const float* wr = Ww + (size_t)j * ND;
        float acc = 0.f;
        for (int k = 0; k < ND; k += 4) {
            float4 w = *(const float4*)(wr + k);
            acc += q[k] * w.x + q[k + 1] * w.y + q[k + 2] * w.z + q[k + 3] * w.w;
        }
        Wq[b * ND + j] = acc + Wb[j];
    }
}

// ---------------- Kernel 2: convert Uw (f32) -> fp16 (RNE) ----------------
__global__ __launch_bounds__(256) void cvt_uw_kernel(const float* __restrict__ Uw,
                                                     _Float16* __restrict__ UwH) {
    const size_t i = ((size_t)blockIdx.x * 256 + threadIdx.x) * 4;
    float4 v = *(const float4*)(Uw + i);
    h4_t h = {(_Float16)v.x, (_Float16)v.y, (_Float16)v.z, (_Float16)v.w};
    *(h4_t*)(UwH + i) = h;
}

// ---------------- Kernel 3: Uk GEMM (fp16 MFMA) + tanh-reduce -> scores ----------------
// BM=64, BN=512 (full), K=512 entirely in LDS (64 KB, transposed [kchunk][row]).
// 8 waves, each owns a 64-row x 64-col output tile (wn = wave).
// ONE barrier after A-staging; K-loop is barrier-free: B double-buffered in regs
// from L2-resident UwH, conflict-free ds_read_b128 for A fragments, 16 MFMA/step.
__global__ __launch_bounds__(512, 4) void uk_score_kernel(
    const float* __restrict__ Km,       // [131072][512] f32
    const _Float16* __restrict__ UwH,   // [512][512] fp16
    const float* __restrict__ Ub,       // [512]
    const float* __restrict__ Wq,       // [64][512]
    const float* __restrict__ Vw,       // [64]
    const float* __restrict__ Vb,       // [1]
    float* __restrict__ scores)         // [512][2048]
{
    // Al[(chunk * 64 + row) * 8 ..] : chunk = k/8 (0..63), row 0..63. 64 KB.
    __shared__ __align__(16) _Float16 Al[64 * 64 * 8];

    const int t = threadIdx.x;
    const int lane = t & 63;
    const int wn = t >> 6;            // 0..7: output column chunk (jb)
    const int col16 = lane & 15;
    const int kg = lane >> 4;         // 0..3

    const int tm = blockIdx.x;        // 0..2047
    const size_t row0 = (size_t)tm * 64;

    // B fragment pointers: row (output col) along K, fp16
    const _Float16* gB[4];
#pragma unroll
    for (int j = 0; j < 4; ++j)
        gB[j] = UwH + (size_t)(wn * 64 + j * 16 + col16) * ND + kg * 8;

    h8_t bf[2][4];
    // issue first B fragments before staging (L2 latency hides under stage)
#pragma unroll
    for (int j = 0; j < 4; ++j) bf[0][j] = *(const h8_t*)(gB[j]);

    // ---- stage A panel: 64 rows x 512 cols f32 -> fp16, transposed LDS ----
    const int arow = t >> 3;          // 0..63
    const int ac8 = t & 7;            // chunk low bits
    const float* gA = Km + (row0 + arow) * (size_t)ND + ac8 * 8;
#pragma unroll
    for (int i = 0; i < 8; ++i) {
        float4 v0 = *(const float4*)(gA + i * 64);
        float4 v1 = *(const float4*)(gA + i * 64 + 4);
        h8_t ah = {(_Float16)v0.x, (_Float16)v0.y, (_Float16)v0.z, (_Float16)v0.w,
                   (_Float16)v1.x, (_Float16)v1.y, (_Float16)v1.z, (_Float16)v1.w};
        *(h8_t*)&Al[(size_t)((ac8 + i * 8) * 64 + arow) * 8] = ah;
    }
    __syncthreads();   // the ONLY barrier

    f32x4 acc[4][4];
#pragma unroll
    for (int i = 0; i < 4; ++i)
#pragma unroll
        for (int j = 0; j < 4; ++j) acc[i][j] = (f32x4){0.f, 0.f, 0.f, 0.f};

#pragma unroll
    for (int s = 0; s < 16; ++s) {
        const int cb = s & 1;
        if (s < 15) {
#pragma unroll
            for (int j = 0; j < 4; ++j)
                bf[cb ^ 1][j] = *(const h8_t*)(gB[j] + (s + 1) * 32);
        }
        h8_t af[4];
#pragma unroll
        for (int i = 0; i < 4; ++i)
            af[i] = *(const h8_t*)&Al[(size_t)((s * 4 + kg) * 64 + i * 16 + col16) * 8];
#pragma unroll
        for (int i = 0; i < 4; ++i)
#pragma unroll
            for (int j = 0; j < 4; ++j)
                acc[i][j] = __builtin_amdgcn_mfma_f32_16x16x32_f16(af[i], bf[cb][j], acc[i][j], 0, 0, 0);
    }

    // epilogue: score(row, jb=wn) = sum_dh tanh(Uk + Wq + Ub) * Vw  (+Vb)
    const int b = (int)(row0 >> 11);
    const int h = ((int)row0 >> 8) & 7;
    const int i256b = (int)row0 & 255;

    float vw[4], wqv[4], ubv[4];
#pragma unroll
    for (int j = 0; j < 4; ++j) {
        const int jglob = wn * 64 + j * 16 + col16;  // 0..511
        const int dh = jglob & 63;
        vw[j] = Vw[dh];
        wqv[j] = Wq[b * ND + h * 64 + dh];
        ubv[j] = Ub[jglob];
    }
    const float vb0 = Vb[0];
    const int jb = wn;                // 0..7
    const int bh = b * 8 + h;

#pragma unroll
    for (int i = 0; i < 4; ++i) {
#pragma unroll
        for (int r = 0; r < 4; ++r) {
            float s = 0.f;
#pragma unroll
            for (int j = 0; j < 4; ++j) {
                float x = acc[i][j][r] + wqv[j] + ubv[j];
                x = fminf(fmaxf(x, -15.f), 15.f);
                float e = __expf(2.f * x);
                s += ((e - 1.f) / (e + 1.f)) * vw[j];
            }
#pragma unroll
            for (int o = 8; o >= 1; o >>= 1) s += __shfl_xor(s, o);
            if (col16 == 0) {
                const int rloc = i * 16 + (lane >> 4) * 4 + r;
                const int m = (i256b + rloc) * 8 + jb;
                scores[(size_t)bh * NL + m] = s + vb0;
            }
        }
    }
}

// ---------------- Kernel 4: softmax -> dist (out) + attn = dist @ Kh ----------------
__global__ __launch_bounds__(256) void softmax_attn_kernel(
    const float* __restrict__ Km,
    const float* __restrict__ scores,
    float* __restrict__ out)  // [0,32768) attn, [32768,...) dist
{
    __shared__ float sd[NL];
    __shared__ float red[256];
    __shared__ float att[16][64];

    const int bh = blockIdx.x;
    const int b = bh >> 3, h = bh & 7;
    const int t = threadIdx.x;

    float loc[8];
    float mx = -1e30f;
#pragma unroll
    for (int j = 0; j < 8; ++j) {
        loc[j] = scores[(size_t)bh * NL + j * 256 + t];
        mx = fmaxf(mx, loc[j]);
    }
    red[t] = mx;
    __syncthreads();
    for (int s2 = 128; s2 > 0; s2 >>= 1) {
        if (t < s2) red[t] = fmaxf(red[t], red[t + s2]);
        __syncthreads();
    }
    mx = red[0];
    __syncthreads();
    float sum = 0.f;
#pragma unroll
    for (int j = 0; j < 8; ++j) {
        loc[j] = __expf(loc[j] - mx);
        sum += loc[j];
    }
    red[t] = sum;
    __syncthreads();
    for (int s2 = 128; s2 > 0; s2 >>= 1) {
        if (t < s2) red[t] += red[t + s2];
        __syncthreads();
    }
    const float inv = 1.f / red[0];
    __syncthreads();

    float* dist_out = out + 32768 + (size_t)bh * NL;
#pragma unroll
    for (int j = 0; j < 8; ++j) {
        float d = loc[j] * inv;
        sd[j * 256 + t] = d;
        dist_out[j * 256 + t] = d;
    }
    __syncthreads();

    const int wave = t >> 6, lane = t & 63;
    const int g = lane >> 4;
    const int c4 = (lane & 15) * 4;
    f32x4 acc = (f32x4){0.f, 0.f, 0.f, 0.f};
    const float* kb = Km + ((size_t)b * NL + h * 256) * ND;
    for (int rr = 0; rr < 16; ++rr) {
        const int row = wave * 64 + rr * 4 + g;
        const float* kr = kb + (size_t)row * ND;
#pragma unroll
        for (int jb2 = 0; jb2 < 8; ++jb2) {
            const float w = sd[row * 8 + jb2];
            float4 v = *(const float4*)(kr + jb2 * 64 + c4);
            acc[0] += w * v.x;
            acc[1] += w * v.y;
            acc[2] += w * v.z;
            acc[3] += w * v.w;
        }
    }
    *(f32x4*)&att[wave * 4 + g][c4] = acc;
    __syncthreads();
    if (t < 64) {
        float a = 0.f;
#pragma unroll
        for (int i = 0; i < 16; ++i) a += att[i][t];
        out[(size_t)b * ND + h * 64 + t] = a;
    }
}

extern "C" void kernel_launch(void* const* d_in, const int* in_sizes, int n_in,
                              void* d_out, int out_size, void* d_ws, size_t ws_size,
                              hipStream_t stream) {
    const float* Q  = (const float*)d_in[0];
    const float* Km = (const float*)d_in[1];
    const float* Ww = (const float*)d_in[2];
    const float* Wb = (const float*)d_in[3];
    const float* Uw = (const float*)d_in[4];
    const float* Ub = (const float*)d_in[5];
    const float* Vw = (const float*)d_in[6];
    const float* Vb = (const float*)d_in[7];
    float* out = (float*)d_out;

    char* ws = (char*)d_ws;
    float* scores = (float*)ws;                              // 4 MB
    float* Wq = (float*)(ws + 4194304);                      // 128 KB
    _Float16* UwH = (_Float16*)(ws + 4194304 + 131072);      // 512 KB

    wq_kernel<<<dim3(64), dim3(256), 0, stream>>>(Q, Ww, Wb, Wq);
    cvt_uw_kernel<<<dim3(256), dim3(256), 0, stream>>>(Uw, UwH);
    uk_score_kernel<<<dim3(2048), dim3(512), 0, stream>>>(Km, UwH, Ub, Wq, Vw, Vb, scores);
    softmax_attn_kernel<<<dim3(512), dim3(256), 0, stream>>>(Km, scores, out);
}